// Round 1
// baseline (4197.485 us; speedup 1.0000x reference)
//
#include <hip/hip_runtime.h>
#include <cmath>

#define HID 64
#define IN_C 128

__device__ __forceinline__ float rl(float v, int k) {
    return __uint_as_float(__builtin_amdgcn_readlane(__float_as_uint(v), k));
}

// ---- CSR build ----------------------------------------------------------

__global__ void k_hist(const int* __restrict__ dst, int* __restrict__ counts, int E) {
    int e = blockIdx.x * blockDim.x + threadIdx.x;
    if (e < E) atomicAdd(&counts[dst[e]], 1);
}

// block-level exclusive scan of counts -> row_ptr (chunk-local), chunk totals out
__global__ void k_scan_block(const int* __restrict__ counts, int* __restrict__ row_ptr,
                             int* __restrict__ chunk_sums, int n) {
    __shared__ int s[1024];
    int i = blockIdx.x * 1024 + threadIdx.x;
    int v = (i < n) ? counts[i] : 0;
    s[threadIdx.x] = v;
    __syncthreads();
    for (int off = 1; off < 1024; off <<= 1) {
        int t = (threadIdx.x >= off) ? s[threadIdx.x - off] : 0;
        __syncthreads();
        s[threadIdx.x] += t;
        __syncthreads();
    }
    if (i < n) row_ptr[i] = s[threadIdx.x] - v;   // exclusive
    if (threadIdx.x == 1023) chunk_sums[blockIdx.x] = s[1023];
}

__global__ void k_scan_fix(int* __restrict__ row_ptr, const int* __restrict__ chunk_sums,
                           int n, int total) {
    __shared__ int base_s;
    if (threadIdx.x == 0) {
        int b = 0;
        for (int c = 0; c < (int)blockIdx.x; ++c) b += chunk_sums[c];
        base_s = b;
    }
    __syncthreads();
    int i = blockIdx.x * 1024 + threadIdx.x;
    if (i < n) row_ptr[i] += base_s;
    if (i == 0) row_ptr[n] = total;
}

__global__ void k_fill(const int* __restrict__ src, const int* __restrict__ dst,
                       const int* __restrict__ row_ptr, int* __restrict__ cursor,
                       int* __restrict__ col_idx, int E) {
    int e = blockIdx.x * blockDim.x + threadIdx.x;
    if (e < E) {
        int d = dst[e];
        int pos = row_ptr[d] + atomicAdd(&cursor[d], 1);
        col_idx[pos] = src[e];
    }
}

// ---- input projection: h0 = relu(x @ lin0_w^T + b) ----------------------
// one wave per node; lane = output channel; W row in registers, x broadcast
// via v_readlane.
__global__ __launch_bounds__(256) void k_lin0(const float* __restrict__ x,
                                              const float* __restrict__ w,
                                              const float* __restrict__ b,
                                              float* __restrict__ h0, int N) {
    int lane = threadIdx.x & 63;
    int wid = (blockIdx.x * blockDim.x + threadIdx.x) >> 6;
    int nw = (gridDim.x * blockDim.x) >> 6;
    float wrow[IN_C];
#pragma unroll
    for (int k = 0; k < IN_C; ++k) wrow[k] = w[lane * IN_C + k];
    float bias = b[lane];
    for (int n = wid; n < N; n += nw) {
        float xv0 = x[(size_t)n * IN_C + lane];
        float xv1 = x[(size_t)n * IN_C + 64 + lane];
        float acc = bias;
#pragma unroll
        for (int k = 0; k < 64; ++k) acc = fmaf(rl(xv0, k), wrow[k], acc);
#pragma unroll
        for (int k = 0; k < 64; ++k) acc = fmaf(rl(xv1, k), wrow[64 + k], acc);
        h0[(size_t)n * HID + lane] = fmaxf(acc, 0.f);
    }
}

// ---- fused GCN2 layer ---------------------------------------------------
// agg (CSR gather) + z = 0.9*agg + 0.1*h0 + GEMM(z @ W) + identity-mix + relu
// one wave per node; lane = channel; W column (W[k][lane]) in 64 VGPRs;
// z_k broadcast via v_readlane.
__global__ __launch_bounds__(256) void k_layer(const float* __restrict__ hin,
                                               const float* __restrict__ h0,
                                               float* __restrict__ hout,
                                               const float* __restrict__ W,
                                               const int* __restrict__ row_ptr,
                                               const int* __restrict__ col_idx,
                                               float beta, int N) {
    int lane = threadIdx.x & 63;
    int wid = (blockIdx.x * blockDim.x + threadIdx.x) >> 6;
    int nw = (gridDim.x * blockDim.x) >> 6;
    float wcol[HID];
#pragma unroll
    for (int k = 0; k < HID; ++k) wcol[k] = W[k * HID + lane];  // coalesced
    for (int n = wid; n < N; n += nw) {
        int beg = row_ptr[n];
        int end = row_ptr[n + 1];
        float acc = 0.f;
        for (int j = beg; j < end; ++j) {
            int s = col_idx[j];
            acc += hin[(size_t)s * HID + lane];  // coalesced 256B row
        }
        float z = 0.9f * acc + 0.1f * h0[(size_t)n * HID + lane];
        float g = 0.f;
#pragma unroll
        for (int k = 0; k < HID; ++k) g = fmaf(rl(z, k), wcol[k], g);
        float r = (1.f - beta) * z + beta * g;
        hout[(size_t)n * HID + lane] = fmaxf(r, 0.f);
    }
}

// ---- output projection: out = h @ lin1_w^T + b --------------------------
__global__ __launch_bounds__(256) void k_lin1(const float* __restrict__ h,
                                              const float* __restrict__ w,
                                              const float* __restrict__ b,
                                              float* __restrict__ out, int N) {
    int lane = threadIdx.x & 63;
    int wid = (blockIdx.x * blockDim.x + threadIdx.x) >> 6;
    int nw = (gridDim.x * blockDim.x) >> 6;
    float wrow[HID];
#pragma unroll
    for (int k = 0; k < HID; ++k) wrow[k] = w[lane * HID + k];
    float bias = b[lane];
    for (int n = wid; n < N; n += nw) {
        float hv = h[(size_t)n * HID + lane];
        float acc = bias;
#pragma unroll
        for (int k = 0; k < HID; ++k) acc = fmaf(rl(hv, k), wrow[k], acc);
        out[(size_t)n * HID + lane] = acc;
    }
}

extern "C" void kernel_launch(void* const* d_in, const int* in_sizes, int n_in,
                              void* d_out, int out_size, void* d_ws, size_t ws_size,
                              hipStream_t stream) {
    const float* x      = (const float*)d_in[0];
    const int*   ei     = (const int*)d_in[1];
    const float* lin0_w = (const float*)d_in[2];
    const float* lin0_b = (const float*)d_in[3];
    const float* lin1_w = (const float*)d_in[4];
    const float* lin1_b = (const float*)d_in[5];
    const float* conv_w = (const float*)d_in[6];

    int N = in_sizes[0] / IN_C;
    int E = in_sizes[1] / 2;
    const int* src = ei;
    const int* dst = ei + E;

    float* h0 = (float*)d_ws;
    float* hA = h0 + (size_t)N * HID;
    float* hB = hA + (size_t)N * HID;
    int* row_ptr    = (int*)(hB + (size_t)N * HID);
    int* cursor     = row_ptr + (N + 1);
    int* col_idx    = cursor + N;
    int* chunk_sums = col_idx + E;

    int nch = (N + 1023) / 1024;

    // CSR build
    hipMemsetAsync(cursor, 0, (size_t)N * sizeof(int), stream);
    k_hist<<<(E + 255) / 256, 256, 0, stream>>>(dst, cursor, E);
    k_scan_block<<<nch, 1024, 0, stream>>>(cursor, row_ptr, chunk_sums, N);
    k_scan_fix<<<nch, 1024, 0, stream>>>(row_ptr, chunk_sums, N, E);
    hipMemsetAsync(cursor, 0, (size_t)N * sizeof(int), stream);
    k_fill<<<(E + 255) / 256, 256, 0, stream>>>(src, dst, row_ptr, cursor, col_idx, E);

    // input projection -> h0 (h starts equal to h0)
    k_lin0<<<1024, 256, 0, stream>>>(x, lin0_w, lin0_b, h0, N);

    // 16 fused layers
    const float* cur = h0;
    for (int l = 0; l < 16; ++l) {
        float beta = (float)log(0.5 / (double)(l + 1) + 1.0);
        float* nxt = (l & 1) ? hB : hA;
        k_layer<<<2048, 256, 0, stream>>>(cur, h0, nxt,
                                          conv_w + (size_t)l * HID * HID,
                                          row_ptr, col_idx, beta, N);
        cur = nxt;
    }

    // output projection
    k_lin1<<<1024, 256, 0, stream>>>(cur, lin1_w, lin1_b, (float*)d_out, N);
}